// Round 11
// baseline (131.587 us; speedup 1.0000x reference)
//
#include <hip/hip_runtime.h>
#include <hip/hip_bf16.h>
#include <math.h>

#define NN    8
#define HH    64
#define WW    64
#define HW    4096
#define NHW   32768
#define EPSBN 1e-5f

// V2 plane geometry: [n][g] planes of [68x68 cells][64 ch], 2-cell zero border
#define PCELLS   4624            // 68*68
#define PELEMS   295936          // 4624*64 shorts per plane
#define ROWS68   4352            // 68*64 shorts per cell-row

typedef __attribute__((ext_vector_type(8))) short short8v;
typedef __attribute__((ext_vector_type(4))) float f32x4;
typedef __attribute__((ext_vector_type(2))) float f32x2;

__device__ __forceinline__ float b2f(unsigned short u) {
    union { unsigned int i; float f; } v; v.i = ((unsigned int)u) << 16; return v.f;
}
__device__ __forceinline__ unsigned short f2b(float f) {
    __hip_bfloat16 h = __float2bfloat16(f);
    return *reinterpret_cast<const unsigned short*>(&h);
}
// dword of 2 bf16 -> f32x2 (lo, hi)
__device__ __forceinline__ f32x2 bf2x(int u) {
    union { int i; float f; } a, b;
    a.i = u << 16;
    b.i = u & 0xffff0000;
    f32x2 r; r[0] = a.f; r[1] = b.f; return r;
}

// Workspace layout (bytes):
//  V2     32 planes x 295936 shorts  @ 0          (18939904)
//  OM     [NHW][112] bf16            @ 18939904   (7340032)
//  y      [NHW][256] bf16            @ 26279936   (16777216)
//  Wallbf [384][256] bf16            @ 43057152   (196608)
//  Woutbf [256][256] bf16            @ 43253760   (131072)
//  ball   [384] f32                  @ 43384832   (1536)
//  bout   [256] f32                  @ 43386368   (1024)

// ---------------- prep_all: tiled weight-fold GEMMs + biases + V2 border zero ----------------
__global__ __launch_bounds__(256)
void prep_all_kernel(const float* __restrict__ cv1_w, const float* __restrict__ cv1_b,
                     const float* __restrict__ value_w, const float* __restrict__ value_b,
                     const float* __restrict__ dw_w, const float* __restrict__ dw_b,
                     const float* __restrict__ om_w, const float* __restrict__ om_b,
                     const float* __restrict__ out_w, const float* __restrict__ cv2_w,
                     const float* __restrict__ bn_g, const float* __restrict__ bn_b,
                     const float* __restrict__ bn_m, const float* __restrict__ bn_v,
                     unsigned short* __restrict__ Wallbf, float* __restrict__ ball,
                     unsigned short* __restrict__ Woutbf, float* __restrict__ bout,
                     unsigned short* __restrict__ V2)
{
    int bid = blockIdx.x;
    int t = threadIdx.x;

    if (bid < 40) {
        // ---- tiled 64x64 GEMM, K=256, BK=16 ----
        __shared__ float As[16][64];
        __shared__ float Bs[16][64];
        int kind, m0, n0;
        if (bid < 16)      { kind = 0; m0 = (bid >> 2) * 64;        n0 = (bid & 3) * 64; }
        else if (bid < 24) { kind = 1; m0 = ((bid - 16) >> 2) * 64; n0 = ((bid - 16) & 3) * 64; }
        else               { kind = 2; m0 = ((bid - 24) >> 2) * 64; n0 = ((bid - 24) & 3) * 64; }

        const float* A = (kind == 0) ? value_w : (kind == 1) ? om_w : cv2_w;
        const float* B = (kind == 2) ? out_w : cv1_w;

        int am = t >> 2, ak4 = (t & 3) * 4;      // A-staging: row m, k-quad
        int bk = t >> 4, bn4 = (t & 15) * 4;     // B-staging: row k, n-quad

        float acc[4][4] = {};
        int px = (t & 15) << 2;
        int dx = (t >> 4) << 2;

        for (int c0 = 0; c0 < 256; c0 += 16) {
            float4 av;
            if (kind == 1 && (m0 + am) >= 112) {
                av = float4{0.f, 0.f, 0.f, 0.f};
            } else {
                av = *reinterpret_cast<const float4*>(&A[(size_t)(m0 + am) * 256 + c0 + ak4]);
                if (kind == 1) {
                    float4 dv = *reinterpret_cast<const float4*>(&dw_w[c0 + ak4]);
                    av.x *= dv.x; av.y *= dv.y; av.z *= dv.z; av.w *= dv.w;
                }
            }
            As[ak4 + 0][am] = av.x;
            As[ak4 + 1][am] = av.y;
            As[ak4 + 2][am] = av.z;
            As[ak4 + 3][am] = av.w;
            *reinterpret_cast<float4*>(&Bs[bk][bn4]) =
                *reinterpret_cast<const float4*>(&B[(size_t)(c0 + bk) * 256 + n0 + bn4]);
            __syncthreads();
            #pragma unroll
            for (int k = 0; k < 16; ++k) {
                float4 a = *reinterpret_cast<const float4*>(&As[k][px]);
                float4 b = *reinterpret_cast<const float4*>(&Bs[k][dx]);
                float avv[4] = {a.x, a.y, a.z, a.w};
                float bvv[4] = {b.x, b.y, b.z, b.w};
                #pragma unroll
                for (int i = 0; i < 4; ++i)
                    #pragma unroll
                    for (int j = 0; j < 4; ++j)
                        acc[i][j] = fmaf(avv[i], bvv[j], acc[i][j]);
            }
            __syncthreads();
        }

        #pragma unroll
        for (int i = 0; i < 4; ++i) {
            int m = m0 + px + i;
            if (kind == 1 && m >= 112) continue;
            float sc = 1.f;
            if (kind == 2) sc = bn_g[m] * rsqrtf(bn_v[m] + EPSBN);
            #pragma unroll
            for (int j = 0; j < 4; ++j) {
                float v = acc[i][j] * sc;
                int cc = n0 + dx + j;
                if (kind == 0)      Wallbf[m * 256 + cc] = f2b(v);
                else if (kind == 1) Wallbf[(256 + m) * 256 + cc] = f2b(v);
                else                Woutbf[m * 256 + cc] = f2b(v);
            }
        }
    } else if (bid == 40) {                     // bv
        int d = t;
        float s = value_b[d];
        for (int e = 0; e < 256; ++e) s = fmaf(value_w[d*256+e], cv1_b[e], s);
        ball[d] = s;
    } else if (bid == 41) {                     // bom + pads
        if (t < 112) {
            float s = om_b[t];
            for (int e = 0; e < 256; ++e)
                s = fmaf(om_w[t*256+e], fmaf(dw_w[e], cv1_b[e], dw_b[e]), s);
            ball[256 + t] = s;
        } else if (t < 128) {
            ball[256 + t] = 0.f;                // ball[368..383]
        }
        // zero Wallbf rows 368..383 (4096 shorts): 16 per thread
        short8v z = {};
        *reinterpret_cast<short8v*>(&Wallbf[368*256 + t*16]) = z;
        *reinterpret_cast<short8v*>(&Wallbf[368*256 + t*16 + 8]) = z;
    } else if (bid == 42) {                     // bout
        float sc = bn_g[t] * rsqrtf(bn_v[t] + EPSBN);
        bout[t] = fmaf(-bn_m[t], sc, bn_b[t]);
    } else {                                    // V2 border zeroing
        int pb = bid - 43;                      // 0..255
        unsigned short* base = V2 + (size_t)(pb >> 3) * PELEMS;
        int off = (pb & 7) * 528;
        for (int ii = t; ii < 528; ii += 256) {
            int idx = off + ii;                 // 0..4223
            int cellsub = idx >> 3;
            int chunk = idx & 7;
            int cell;
            if (cellsub < 272) {
                int r = cellsub / 68;
                int c = cellsub - r * 68;
                int row = (r < 2) ? r : r + 62;
                cell = row * 68 + c;
            } else {
                int i2 = cellsub - 272;
                int row = 2 + (i2 >> 2);
                int cs = i2 & 3;
                int col = (cs < 2) ? cs : cs + 62;
                cell = row * 68 + col;
            }
            *reinterpret_cast<int4*>(&base[cell * 64 + chunk * 8]) = int4{0,0,0,0};
        }
    }
}

// ---------------- GEMM1 (fused x-transpose): [V2|OM] = bf16(x)^T @ Wallbf^T + ball ----------------
__global__ __launch_bounds__(256)
void gemm_vo_kernel(const float* __restrict__ x, const unsigned short* __restrict__ Wallbf,
                    const float* __restrict__ ball,
                    unsigned short* __restrict__ V2, unsigned short* __restrict__ OM)
{
    __shared__ unsigned short As[8192];
    __shared__ unsigned short Bs[8192];
    int t = threadIdx.x;
    int m0 = blockIdx.y * 128;   // pixel tile
    int n0 = blockIdx.x * 128;   // output-channel tile
    int nimg = m0 >> 12, hw0 = m0 & 4095;
    int lane = t & 63;
    int wv = t >> 6;
    int wr = wv >> 1, wc = wv & 1;
    int r_l = lane & 15, kg_l = lane >> 4;
    int ci = t >> 6;             // c-chunk (16 ch) for A staging
    int l  = t & 63;             // row-pair for A staging

    const float* xbase = x + (size_t)(nimg * 256) * 4096 + hw0;

    f32x4 acc[4][4] = {};

    for (int kt = 0; kt < 4; ++kt) {
        int c0 = kt * 64;
        float2 val[16];
        #pragma unroll
        for (int i = 0; i < 16; ++i)
            val[i] = *reinterpret_cast<const float2*>(
                &xbase[(size_t)(c0 + ci*16 + i) * 4096 + 2*l]);
        __syncthreads();   // prior MFMA reads done before overwrite
        #pragma unroll
        for (int rsel = 0; rsel < 2; ++rsel) {
            int row = 2*l + rsel;
            #pragma unroll
            for (int kgi = 0; kgi < 2; ++kgi) {
                int kg = ci*2 + kgi;
                short8v s;
                #pragma unroll
                for (int j = 0; j < 8; ++j)
                    s[j] = (short)f2b(rsel ? val[kgi*8+j].y : val[kgi*8+j].x);
                *reinterpret_cast<short8v*>(&As[row*64 + ((kg ^ (row & 7)) << 3)]) = s;
            }
        }
        #pragma unroll
        for (int i = 0; i < 4; ++i) {
            int idx = t + i*256;
            int row = idx >> 3, kg = idx & 7;
            *reinterpret_cast<short8v*>(&Bs[row*64 + ((kg ^ (row & 7)) << 3)]) =
                *reinterpret_cast<const short8v*>(&Wallbf[(size_t)(n0 + row)*256 + c0 + kg*8]);
        }
        __syncthreads();
        #pragma unroll
        for (int ks = 0; ks < 2; ++ks) {
            short8v af[4], bfr[4];
            #pragma unroll
            for (int m = 0; m < 4; ++m) {
                int row = wr*64 + m*16 + r_l;
                af[m] = *reinterpret_cast<const short8v*>(
                    &As[row*64 + (((ks*4 + kg_l) ^ (row & 7)) << 3)]);
            }
            #pragma unroll
            for (int n = 0; n < 4; ++n) {
                int row = wc*64 + n*16 + r_l;
                bfr[n] = *reinterpret_cast<const short8v*>(
                    &Bs[row*64 + (((ks*4 + kg_l) ^ (row & 7)) << 3)]);
            }
            #pragma unroll
            for (int m = 0; m < 4; ++m)
                #pragma unroll
                for (int n = 0; n < 4; ++n)
                    acc[m][n] = __builtin_amdgcn_mfma_f32_16x16x32_bf16(af[m], bfr[n], acc[m][n], 0, 0, 0);
        }
    }

    #pragma unroll
    for (int n = 0; n < 4; ++n) {
        int d = n0 + wc*64 + n*16 + r_l;
        float bb = ball[d];
        #pragma unroll
        for (int m = 0; m < 4; ++m) {
            int pr = m0 + wr*64 + m*16 + (kg_l << 2);
            #pragma unroll
            for (int r = 0; r < 4; ++r) {
                float res = acc[m][n][r] + bb;
                int p = pr + r;
                if (d < 256) {
                    int g = d >> 6, ch = d & 63;
                    int hw = p & 4095;
                    int yy = hw >> 6, xx = hw & 63;
                    size_t cell = (size_t)((p >> 12)*4 + g) * PCELLS + (yy + 2)*68 + (xx + 2);
                    V2[cell * 64 + ch] = f2b(res);
                } else if (d < 368) {
                    OM[(size_t)p * 112 + (d - 256)] = f2b(res);
                }
            }
        }
    }
}

// ---------------- shared MFMA mainloop (for GEMM2) ----------------
__device__ __forceinline__
void gemm_mainloop(const unsigned short* __restrict__ A, const unsigned short* __restrict__ B,
                   int m0, int n0, unsigned short* As, unsigned short* Bs,
                   f32x4 (&acc)[4][4], int t)
{
    int lane = t & 63;
    int wv = t >> 6;
    int wr = wv >> 1, wc = wv & 1;
    int r_l = lane & 15;
    int kg_l = lane >> 4;

    for (int kt = 0; kt < 4; ++kt) {
        int c0 = kt * 64;
        #pragma unroll
        for (int i = 0; i < 4; ++i) {
            int idx = t + i * 256;
            int kg = idx & 7, row = idx >> 3;
            int soff = row*64 + ((kg ^ (row & 7)) << 3);
            *reinterpret_cast<short8v*>(&As[soff]) =
                *reinterpret_cast<const short8v*>(&A[(size_t)(m0 + row)*256 + c0 + kg*8]);
            *reinterpret_cast<short8v*>(&Bs[soff]) =
                *reinterpret_cast<const short8v*>(&B[(size_t)(n0 + row)*256 + c0 + kg*8]);
        }
        __syncthreads();
        #pragma unroll
        for (int ks = 0; ks < 2; ++ks) {
            short8v af[4], bfr[4];
            #pragma unroll
            for (int m = 0; m < 4; ++m) {
                int row = wr*64 + m*16 + r_l;
                af[m] = *reinterpret_cast<const short8v*>(
                    &As[row*64 + (((ks*4 + kg_l) ^ (row & 7)) << 3)]);
            }
            #pragma unroll
            for (int n = 0; n < 4; ++n) {
                int row = wc*64 + n*16 + r_l;
                bfr[n] = *reinterpret_cast<const short8v*>(
                    &Bs[row*64 + (((ks*4 + kg_l) ^ (row & 7)) << 3)]);
            }
            #pragma unroll
            for (int m = 0; m < 4; ++m)
                #pragma unroll
                for (int n = 0; n < 4; ++n)
                    acc[m][n] = __builtin_amdgcn_mfma_f32_16x16x32_bf16(af[m], bfr[n], acc[m][n], 0, 0, 0);
        }
        __syncthreads();
    }
}

// ---------------- GEMM2 (transposed): out = SiLU(Wout @ y^T + bout), NCHW f32 ----------------
__global__ __launch_bounds__(256)
void gemm_out_kernel(const unsigned short* __restrict__ Woutbf, const unsigned short* __restrict__ y,
                     const float* __restrict__ bout, float* __restrict__ out)
{
    __shared__ unsigned short lds[2 * 8192];
    int t = threadIdx.x;
    int m0 = blockIdx.x * 128;   // d tile
    int n0 = blockIdx.y * 128;   // pixel tile
    f32x4 acc[4][4] = {};
    gemm_mainloop(Woutbf, y, m0, n0, lds, lds + 8192, acc, t);

    int lane = t & 63;
    int wv = t >> 6, wr = wv >> 1, wc = wv & 1;
    int r_l = lane & 15, kg_l = lane >> 4;
    int nimg = n0 >> 12;
    int hwb = n0 & 4095;
    #pragma unroll
    for (int m = 0; m < 4; ++m) {
        int dbase = m0 + wr*64 + m*16 + (kg_l << 2);
        #pragma unroll
        for (int r = 0; r < 4; ++r) {
            int d = dbase + r;
            float bb = bout[d];
            #pragma unroll
            for (int n = 0; n < 4; ++n) {
                int pcol = wc*64 + n*16 + r_l;
                float z = acc[m][n][r] + bb;
                float sv = z / (1.f + __expf(-z));
                out[((size_t)(nimg*256 + d))*4096 + hwb + pcol] = sv;
            }
        }
    }
}

// ---------------- DCNv4 core: LDS row-slab, block = 1 image row x 1 group ----------------
// Stage padded rows h..h+4 (contiguous 43.5KB slab) of one plane into LDS with
// XOR swizzle (ch8 ^= cell&7) -> conflict-free ds_read_b128 corner loads.
// px clamped to [-1,64] never escapes the staged row in x; only |dy|>=1 can
// escape in y (~10-sigma) -> per-tap lr<4 check with global fallback (exact).
__global__ __launch_bounds__(512)
void dcn_kernel(const unsigned short* __restrict__ V2, const unsigned short* __restrict__ OM,
                unsigned short* __restrict__ y)
{
    __shared__ unsigned short vs[5 * 68 * 64];   // 43520 B, swizzled
    __shared__ float om_s[64][27];               // 6912 B
    int t = threadIdx.x;
    int bid = blockIdx.x;                        // 2048 = 8 XCD x 256
    int logical = ((bid & 7) << 8) + (bid >> 3); // image == XCD
    int n = logical >> 8;
    int rowg = logical & 255;
    int h = rowg >> 2, g = rowg & 3;
    int p0 = n * 4096 + h * 64;

    const unsigned short* plane = V2 + (size_t)(n*4 + g) * PELEMS;

    // stage rows h..h+4 (padded coords), full 68 cells, swizzled
    {
        const int4* src = reinterpret_cast<const int4*>(plane + (size_t)h * ROWS68);
        for (int i = t; i < 2720; i += 512) {
            int cell = i >> 3, c8 = i & 7;
            *reinterpret_cast<int4*>(&vs[cell*64 + ((c8 ^ (cell & 7)) << 3)]) = src[i];
        }
    }
    for (int i = t; i < 1728; i += 512) {
        int pl = i / 27, j = i - pl * 27;
        om_s[pl][j] = b2f(OM[(size_t)(p0 + pl)*112 + g*27 + j]);
    }
    __syncthreads();

    int pl = t >> 3, ch8 = t & 7;                // wave = 8 px x 8 ch-lanes
    int p = p0 + pl;
    int w = pl;
    const float* o = om_s[pl];
    const unsigned short* gbase = plane + ch8*8; // fallback path

    f32x2 acc2[4] = {};
    #pragma unroll
    for (int k = 0; k < 9; ++k) {
        float dxo = o[2*k], dyo = o[2*k+1], m = o[18+k];
        float px = fminf(fmaxf((float)(w + (k % 3) - 1) + dxo, -1.f), 64.f);
        float py = fminf(fmaxf((float)(h + (k / 3) - 1) + dyo, -1.f), 64.f);
        float x0f = floorf(px), y0f = floorf(py);
        float fx = px - x0f, fy = py - y0f;
        float gx = 1.f - fx, gy = 1.f - fy;
        int x0 = (int)x0f, y0 = (int)y0f;
        int lr = y0 + 2 - h;                     // LDS row of top corners
        int4 v00, v01, v10, v11;
        if ((unsigned)lr < 4u) {
            int cA = lr*68 + x0 + 2;
            int cB = cA + 1, cC = cA + 68, cD = cA + 69;
            v00 = *reinterpret_cast<const int4*>(&vs[cA*64 + ((ch8 ^ (cA & 7)) << 3)]);
            v01 = *reinterpret_cast<const int4*>(&vs[cB*64 + ((ch8 ^ (cB & 7)) << 3)]);
            v10 = *reinterpret_cast<const int4*>(&vs[cC*64 + ((ch8 ^ (cC & 7)) << 3)]);
            v11 = *reinterpret_cast<const int4*>(&vs[cD*64 + ((ch8 ^ (cD & 7)) << 3)]);
        } else {
            int gc = (y0 + 2)*68 + x0 + 2;
            const unsigned short* cp0 = gbase + gc * 64;
            const unsigned short* cp1 = cp0 + ROWS68;
            v00 = *reinterpret_cast<const int4*>(cp0);
            v01 = *reinterpret_cast<const int4*>(cp0 + 64);
            v10 = *reinterpret_cast<const int4*>(cp1);
            v11 = *reinterpret_cast<const int4*>(cp1 + 64);
        }
        float gym = gy * m, fym = fy * m;
        float w00 = gym*gx, w01 = gym*fx, w10 = fym*gx, w11 = fym*fx;
        {
            f32x2 W; W[0] = w00; W[1] = w00;
            int a[4] = {v00.x, v00.y, v00.z, v00.w};
            #pragma unroll
            for (int q = 0; q < 4; ++q) acc2[q] += bf2x(a[q]) * W;
        }
        {
            f32x2 W; W[0] = w01; W[1] = w01;
            int a[4] = {v01.x, v01.y, v01.z, v01.w};
            #pragma unroll
            for (int q = 0; q < 4; ++q) acc2[q] += bf2x(a[q]) * W;
        }
        {
            f32x2 W; W[0] = w10; W[1] = w10;
            int a[4] = {v10.x, v10.y, v10.z, v10.w};
            #pragma unroll
            for (int q = 0; q < 4; ++q) acc2[q] += bf2x(a[q]) * W;
        }
        {
            f32x2 W; W[0] = w11; W[1] = w11;
            int a[4] = {v11.x, v11.y, v11.z, v11.w};
            #pragma unroll
            for (int q = 0; q < 4; ++q) acc2[q] += bf2x(a[q]) * W;
        }
    }

    short8v ov;
    #pragma unroll
    for (int q = 0; q < 4; ++q) {
        ov[2*q]   = (short)f2b(acc2[q][0]);
        ov[2*q+1] = (short)f2b(acc2[q][1]);
    }
    *reinterpret_cast<short8v*>(&y[(size_t)p*256 + g*64 + ch8*8]) = ov;
}

extern "C" void kernel_launch(void* const* d_in, const int* in_sizes, int n_in,
                              void* d_out, int out_size, void* d_ws, size_t ws_size,
                              hipStream_t stream) {
    const float* x       = (const float*)d_in[0];
    const float* cv1_w   = (const float*)d_in[1];
    const float* cv1_b   = (const float*)d_in[2];
    const float* value_w = (const float*)d_in[3];
    const float* value_b = (const float*)d_in[4];
    const float* dw_w    = (const float*)d_in[5];
    const float* dw_b    = (const float*)d_in[6];
    const float* om_w    = (const float*)d_in[7];
    const float* om_b    = (const float*)d_in[8];
    const float* out_w   = (const float*)d_in[9];
    const float* cv2_w   = (const float*)d_in[10];
    const float* bn_g    = (const float*)d_in[11];
    const float* bn_b    = (const float*)d_in[12];
    const float* bn_m    = (const float*)d_in[13];
    const float* bn_v    = (const float*)d_in[14];

    char* ws = (char*)d_ws;
    unsigned short* V2     = (unsigned short*)(ws);
    unsigned short* OM     = (unsigned short*)(ws + 18939904);
    unsigned short* y      = (unsigned short*)(ws + 26279936);
    unsigned short* Wallbf = (unsigned short*)(ws + 43057152);
    unsigned short* Woutbf = (unsigned short*)(ws + 43253760);
    float*          ball   = (float*)(ws + 43384832);
    float*          bout   = (float*)(ws + 43386368);
    float* out = (float*)d_out;

    prep_all_kernel<<<299, 256, 0, stream>>>(cv1_w, cv1_b, value_w, value_b, dw_w, dw_b,
                                             om_w, om_b, out_w, cv2_w,
                                             bn_g, bn_b, bn_m, bn_v,
                                             Wallbf, ball, Woutbf, bout, V2);
    gemm_vo_kernel<<<dim3(3, 256), 256, 0, stream>>>(x, Wallbf, ball, V2, OM);
    dcn_kernel<<<2048, 512, 0, stream>>>(V2, OM, y);
    gemm_out_kernel<<<dim3(2, 256), 256, 0, stream>>>(Woutbf, y, bout, out);
}

// Round 12
// 95.703 us; speedup vs baseline: 1.3750x; 1.3750x over previous
//
#include <hip/hip_runtime.h>
#include <hip/hip_bf16.h>
#include <math.h>

#define NN    8
#define HH    64
#define WW    64
#define HW    4096
#define NHW   32768
#define DALL  384     // 256 value + 112 om + 16 pad
#define EPSBN 1e-5f

typedef __attribute__((ext_vector_type(8))) short short8v;
typedef __attribute__((ext_vector_type(4))) float f32x4;
typedef __attribute__((ext_vector_type(2))) float f32x2;

__device__ __forceinline__ float b2f(unsigned short u) {
    union { unsigned int i; float f; } v; v.i = ((unsigned int)u) << 16; return v.f;
}
__device__ __forceinline__ unsigned short f2b(float f) {
    __hip_bfloat16 h = __float2bfloat16(f);
    return *reinterpret_cast<const unsigned short*>(&h);
}
// dword of 2 bf16 -> f32x2 (lo, hi)
__device__ __forceinline__ f32x2 bf2x(int u) {
    union { int i; float f; } a, b;
    a.i = u << 16;
    b.i = u & 0xffff0000;
    f32x2 r; r[0] = a.f; r[1] = b.f; return r;
}

// Workspace layout (bytes):
//  VO     [NHW][384] bf16  @ 0          (25165824)
//  y      [NHW][256] bf16  @ 25165824   (16777216)
//  Wallbf [384][256] bf16  @ 41943040   (196608)
//  Woutbf [256][256] bf16  @ 42139648   (131072)
//  ball   [384] f32        @ 42270720   (1536)
//  bout   [256] f32        @ 42272256   (1024)

// ---------------- prep_all: tiled weight-fold GEMMs + biases ----------------
// blocks 0..15 : Wv[256x256]  = value_w @ cv1_w
// blocks 16..23: Wom[112x256] = (om_w . dw_w) @ cv1_w  (rows >=112 guarded)
// blocks 24..39: Wout[256x256]= diag(sc) cv2_w @ out_w
// block  40    : bv   | block 41: bom + pads | block 42: bout
__global__ __launch_bounds__(256)
void prep_all_kernel(const float* __restrict__ cv1_w, const float* __restrict__ cv1_b,
                     const float* __restrict__ value_w, const float* __restrict__ value_b,
                     const float* __restrict__ dw_w, const float* __restrict__ dw_b,
                     const float* __restrict__ om_w, const float* __restrict__ om_b,
                     const float* __restrict__ out_w, const float* __restrict__ cv2_w,
                     const float* __restrict__ bn_g, const float* __restrict__ bn_b,
                     const float* __restrict__ bn_m, const float* __restrict__ bn_v,
                     unsigned short* __restrict__ Wallbf, float* __restrict__ ball,
                     unsigned short* __restrict__ Woutbf, float* __restrict__ bout)
{
    int bid = blockIdx.x;
    int t = threadIdx.x;

    if (bid < 40) {
        __shared__ float As[16][64];
        __shared__ float Bs[16][64];
        int kind, m0, n0;
        if (bid < 16)      { kind = 0; m0 = (bid >> 2) * 64;        n0 = (bid & 3) * 64; }
        else if (bid < 24) { kind = 1; m0 = ((bid - 16) >> 2) * 64; n0 = ((bid - 16) & 3) * 64; }
        else               { kind = 2; m0 = ((bid - 24) >> 2) * 64; n0 = ((bid - 24) & 3) * 64; }

        const float* A = (kind == 0) ? value_w : (kind == 1) ? om_w : cv2_w;
        const float* B = (kind == 2) ? out_w : cv1_w;

        int am = t >> 2, ak4 = (t & 3) * 4;      // A-staging: row m, k-quad
        int bk = t >> 4, bn4 = (t & 15) * 4;     // B-staging: row k, n-quad

        float acc[4][4] = {};
        int px = (t & 15) << 2;
        int dx = (t >> 4) << 2;

        for (int c0 = 0; c0 < 256; c0 += 16) {
            float4 av;
            if (kind == 1 && (m0 + am) >= 112) {
                av = float4{0.f, 0.f, 0.f, 0.f};
            } else {
                av = *reinterpret_cast<const float4*>(&A[(size_t)(m0 + am) * 256 + c0 + ak4]);
                if (kind == 1) {
                    float4 dv = *reinterpret_cast<const float4*>(&dw_w[c0 + ak4]);
                    av.x *= dv.x; av.y *= dv.y; av.z *= dv.z; av.w *= dv.w;
                }
            }
            As[ak4 + 0][am] = av.x;
            As[ak4 + 1][am] = av.y;
            As[ak4 + 2][am] = av.z;
            As[ak4 + 3][am] = av.w;
            *reinterpret_cast<float4*>(&Bs[bk][bn4]) =
                *reinterpret_cast<const float4*>(&B[(size_t)(c0 + bk) * 256 + n0 + bn4]);
            __syncthreads();
            #pragma unroll
            for (int k = 0; k < 16; ++k) {
                float4 a = *reinterpret_cast<const float4*>(&As[k][px]);
                float4 b = *reinterpret_cast<const float4*>(&Bs[k][dx]);
                float avv[4] = {a.x, a.y, a.z, a.w};
                float bvv[4] = {b.x, b.y, b.z, b.w};
                #pragma unroll
                for (int i = 0; i < 4; ++i)
                    #pragma unroll
                    for (int j = 0; j < 4; ++j)
                        acc[i][j] = fmaf(avv[i], bvv[j], acc[i][j]);
            }
            __syncthreads();
        }

        #pragma unroll
        for (int i = 0; i < 4; ++i) {
            int m = m0 + px + i;
            if (kind == 1 && m >= 112) continue;
            float sc = 1.f;
            if (kind == 2) sc = bn_g[m] * rsqrtf(bn_v[m] + EPSBN);
            #pragma unroll
            for (int j = 0; j < 4; ++j) {
                float v = acc[i][j] * sc;
                int cc = n0 + dx + j;
                if (kind == 0)      Wallbf[m * 256 + cc] = f2b(v);
                else if (kind == 1) Wallbf[(256 + m) * 256 + cc] = f2b(v);
                else                Woutbf[m * 256 + cc] = f2b(v);
            }
        }
    } else if (bid == 40) {                     // bv
        int d = t;
        float s = value_b[d];
        for (int e = 0; e < 256; ++e) s = fmaf(value_w[d*256+e], cv1_b[e], s);
        ball[d] = s;
    } else if (bid == 41) {                     // bom + pads
        if (t < 112) {
            float s = om_b[t];
            for (int e = 0; e < 256; ++e)
                s = fmaf(om_w[t*256+e], fmaf(dw_w[e], cv1_b[e], dw_b[e]), s);
            ball[256 + t] = s;
        } else if (t < 128) {
            ball[256 + t] = 0.f;                // ball[368..383]
        }
        // zero Wallbf rows 368..383 (4096 shorts): 16 per thread
        short8v z = {};
        *reinterpret_cast<short8v*>(&Wallbf[368*256 + t*16]) = z;
        *reinterpret_cast<short8v*>(&Wallbf[368*256 + t*16 + 8]) = z;
    } else {                                    // bout
        float sc = bn_g[t] * rsqrtf(bn_v[t] + EPSBN);
        bout[t] = fmaf(-bn_m[t], sc, bn_b[t]);
    }
}

// ---------------- GEMM1 (fused x-transpose): VO = bf16(x)^T @ Wallbf^T + ball ----------------
// grid (3, 256): n-tile fastest so the 3 n-tiles of one pixel tile dispatch
// adjacently and share the x tile through L2/L3.
__global__ __launch_bounds__(256)
void gemm_vo_kernel(const float* __restrict__ x, const unsigned short* __restrict__ Wallbf,
                    const float* __restrict__ ball, unsigned short* __restrict__ VO)
{
    __shared__ unsigned short As[8192];
    __shared__ unsigned short Bs[8192];
    int t = threadIdx.x;
    int m0 = blockIdx.y * 128;   // pixel tile
    int n0 = blockIdx.x * 128;   // output-channel tile
    int nimg = m0 >> 12, hw0 = m0 & 4095;
    int lane = t & 63;
    int wv = t >> 6;
    int wr = wv >> 1, wc = wv & 1;
    int r_l = lane & 15, kg_l = lane >> 4;
    int ci = t >> 6;             // c-chunk (16 ch) for A staging
    int l  = t & 63;             // row-pair for A staging

    const float* xbase = x + (size_t)(nimg * 256) * 4096 + hw0;

    f32x4 acc[4][4] = {};

    for (int kt = 0; kt < 4; ++kt) {
        int c0 = kt * 64;
        float2 val[16];
        #pragma unroll
        for (int i = 0; i < 16; ++i)
            val[i] = *reinterpret_cast<const float2*>(
                &xbase[(size_t)(c0 + ci*16 + i) * 4096 + 2*l]);
        __syncthreads();   // prior MFMA reads done before overwrite
        #pragma unroll
        for (int rsel = 0; rsel < 2; ++rsel) {
            int row = 2*l + rsel;
            #pragma unroll
            for (int kgi = 0; kgi < 2; ++kgi) {
                int kg = ci*2 + kgi;
                short8v s;
                #pragma unroll
                for (int j = 0; j < 8; ++j)
                    s[j] = (short)f2b(rsel ? val[kgi*8+j].y : val[kgi*8+j].x);
                *reinterpret_cast<short8v*>(&As[row*64 + ((kg ^ (row & 7)) << 3)]) = s;
            }
        }
        #pragma unroll
        for (int i = 0; i < 4; ++i) {
            int idx = t + i*256;
            int row = idx >> 3, kg = idx & 7;
            *reinterpret_cast<short8v*>(&Bs[row*64 + ((kg ^ (row & 7)) << 3)]) =
                *reinterpret_cast<const short8v*>(&Wallbf[(size_t)(n0 + row)*256 + c0 + kg*8]);
        }
        __syncthreads();
        #pragma unroll
        for (int ks = 0; ks < 2; ++ks) {
            short8v af[4], bfr[4];
            #pragma unroll
            for (int m = 0; m < 4; ++m) {
                int row = wr*64 + m*16 + r_l;
                af[m] = *reinterpret_cast<const short8v*>(
                    &As[row*64 + (((ks*4 + kg_l) ^ (row & 7)) << 3)]);
            }
            #pragma unroll
            for (int n = 0; n < 4; ++n) {
                int row = wc*64 + n*16 + r_l;
                bfr[n] = *reinterpret_cast<const short8v*>(
                    &Bs[row*64 + (((ks*4 + kg_l) ^ (row & 7)) << 3)]);
            }
            #pragma unroll
            for (int m = 0; m < 4; ++m)
                #pragma unroll
                for (int n = 0; n < 4; ++n)
                    acc[m][n] = __builtin_amdgcn_mfma_f32_16x16x32_bf16(af[m], bfr[n], acc[m][n], 0, 0, 0);
        }
    }

    #pragma unroll
    for (int n = 0; n < 4; ++n) {
        int d = n0 + wc*64 + n*16 + r_l;
        float bb = ball[d];
        #pragma unroll
        for (int m = 0; m < 4; ++m) {
            int pr = m0 + wr*64 + m*16 + (kg_l << 2);
            #pragma unroll
            for (int r = 0; r < 4; ++r)
                VO[(size_t)(pr + r)*384 + d] = f2b(acc[m][n][r] + bb);
        }
    }
}

// ---------------- shared MFMA mainloop (for GEMM2) ----------------
__device__ __forceinline__
void gemm_mainloop(const unsigned short* __restrict__ A, const unsigned short* __restrict__ B,
                   int m0, int n0, unsigned short* As, unsigned short* Bs,
                   f32x4 (&acc)[4][4], int t)
{
    int lane = t & 63;
    int wv = t >> 6;
    int wr = wv >> 1, wc = wv & 1;
    int r_l = lane & 15;
    int kg_l = lane >> 4;

    for (int kt = 0; kt < 4; ++kt) {
        int c0 = kt * 64;
        #pragma unroll
        for (int i = 0; i < 4; ++i) {
            int idx = t + i * 256;
            int kg = idx & 7, row = idx >> 3;
            int soff = row*64 + ((kg ^ (row & 7)) << 3);
            *reinterpret_cast<short8v*>(&As[soff]) =
                *reinterpret_cast<const short8v*>(&A[(size_t)(m0 + row)*256 + c0 + kg*8]);
            *reinterpret_cast<short8v*>(&Bs[soff]) =
                *reinterpret_cast<const short8v*>(&B[(size_t)(n0 + row)*256 + c0 + kg*8]);
        }
        __syncthreads();
        #pragma unroll
        for (int ks = 0; ks < 2; ++ks) {
            short8v af[4], bfr[4];
            #pragma unroll
            for (int m = 0; m < 4; ++m) {
                int row = wr*64 + m*16 + r_l;
                af[m] = *reinterpret_cast<const short8v*>(
                    &As[row*64 + (((ks*4 + kg_l) ^ (row & 7)) << 3)]);
            }
            #pragma unroll
            for (int n = 0; n < 4; ++n) {
                int row = wc*64 + n*16 + r_l;
                bfr[n] = *reinterpret_cast<const short8v*>(
                    &Bs[row*64 + (((ks*4 + kg_l) ^ (row & 7)) << 3)]);
            }
            #pragma unroll
            for (int m = 0; m < 4; ++m)
                #pragma unroll
                for (int n = 0; n < 4; ++n)
                    acc[m][n] = __builtin_amdgcn_mfma_f32_16x16x32_bf16(af[m], bfr[n], acc[m][n], 0, 0, 0);
        }
        __syncthreads();
    }
}

// ---------------- GEMM2 (transposed): out = SiLU(Wout @ y^T + bout), NCHW f32 ----------------
__global__ __launch_bounds__(256)
void gemm_out_kernel(const unsigned short* __restrict__ Woutbf, const unsigned short* __restrict__ y,
                     const float* __restrict__ bout, float* __restrict__ out)
{
    __shared__ unsigned short lds[2 * 8192];
    int t = threadIdx.x;
    int m0 = blockIdx.x * 128;   // d tile
    int n0 = blockIdx.y * 128;   // pixel tile
    f32x4 acc[4][4] = {};
    gemm_mainloop(Woutbf, y, m0, n0, lds, lds + 8192, acc, t);

    int lane = t & 63;
    int wv = t >> 6, wr = wv >> 1, wc = wv & 1;
    int r_l = lane & 15, kg_l = lane >> 4;
    int nimg = n0 >> 12;
    int hwb = n0 & 4095;
    #pragma unroll
    for (int m = 0; m < 4; ++m) {
        int dbase = m0 + wr*64 + m*16 + (kg_l << 2);
        #pragma unroll
        for (int r = 0; r < 4; ++r) {
            int d = dbase + r;
            float bb = bout[d];
            #pragma unroll
            for (int n = 0; n < 4; ++n) {
                int pcol = wc*64 + n*16 + r_l;
                float z = acc[m][n][r] + bb;
                float sv = z / (1.f + __expf(-z));
                out[((size_t)(nimg*256 + d))*4096 + hwb + pcol] = sv;
            }
        }
    }
}

// ---------------- DCNv4 core: 8 ch/lane, direct global loads, pk-f32x2 accum ----------------
__global__ __launch_bounds__(256)
void dcn_kernel(const unsigned short* __restrict__ VO, unsigned short* __restrict__ y)
{
    __shared__ float om_s[8][108];
    int t = threadIdx.x;
    int bid = blockIdx.x;
    int logical = ((bid & 7) << 9) + (bid >> 3);   // image == XCD
    int p0 = logical * 8;

    for (int i = t; i < 864; i += 256) {
        int pl = i / 108, j = i - pl * 108;
        om_s[pl][j] = b2f(VO[(size_t)(p0 + pl)*384 + 256 + j]);
    }
    __syncthreads();

    int slot = t >> 3, ch8 = t & 7;
    int pl = slot >> 2, g = slot & 3;
    int p = p0 + pl;
    int hw = p & 4095;
    int h = hw >> 6, w = hw & 63;
    const unsigned short* vbase = VO + (size_t)(p >> 12) * (HW * (size_t)DALL) + g*64 + ch8*8;
    const float* o = &om_s[pl][g*27];

    f32x2 acc2[4] = {};
    #pragma unroll
    for (int k = 0; k < 9; ++k) {
        float dxo = o[2*k], dyo = o[2*k+1], m = o[18+k];
        float pxf = (float)(w + (k % 3) - 1) + dxo;
        float pyf = (float)(h + (k / 3) - 1) + dyo;
        float x0f = floorf(pxf), y0f = floorf(pyf);
        float fx = pxf - x0f, fy = pyf - y0f;
        int x0 = (int)x0f, y0 = (int)y0f;
        #pragma unroll
        for (int dyy = 0; dyy < 2; ++dyy) {
            #pragma unroll
            for (int dxx = 0; dxx < 2; ++dxx) {
                int yy = y0 + dyy, xx = x0 + dxx;
                bool valid = (yy >= 0) & (yy < HH) & (xx >= 0) & (xx < WW);
                float wgt = (dyy ? fy : 1.f - fy) * (dxx ? fx : 1.f - fx);
                float wmc = valid ? (m * wgt) : 0.f;
                int yc = min(max(yy, 0), HH - 1);
                int xc = min(max(xx, 0), WW - 1);
                int4 v = *reinterpret_cast<const int4*>(
                    &vbase[((yc << 6) + xc) * DALL]);
                f32x2 wm2; wm2[0] = wmc; wm2[1] = wmc;
                int vv[4] = {v.x, v.y, v.z, v.w};
                #pragma unroll
                for (int q = 0; q < 4; ++q)
                    acc2[q] += bf2x(vv[q]) * wm2;
            }
        }
    }
    short8v ov;
    #pragma unroll
    for (int q = 0; q < 4; ++q) {
        ov[2*q]   = (short)f2b(acc2[q][0]);
        ov[2*q+1] = (short)f2b(acc2[q][1]);
    }
    *reinterpret_cast<short8v*>(&y[(size_t)p*256 + g*64 + ch8*8]) = ov;
}

extern "C" void kernel_launch(void* const* d_in, const int* in_sizes, int n_in,
                              void* d_out, int out_size, void* d_ws, size_t ws_size,
                              hipStream_t stream) {
    const float* x       = (const float*)d_in[0];
    const float* cv1_w   = (const float*)d_in[1];
    const float* cv1_b   = (const float*)d_in[2];
    const float* value_w = (const float*)d_in[3];
    const float* value_b = (const float*)d_in[4];
    const float* dw_w    = (const float*)d_in[5];
    const float* dw_b    = (const float*)d_in[6];
    const float* om_w    = (const float*)d_in[7];
    const float* om_b    = (const float*)d_in[8];
    const float* out_w   = (const float*)d_in[9];
    const float* cv2_w   = (const float*)d_in[10];
    const float* bn_g    = (const float*)d_in[11];
    const float* bn_b    = (const float*)d_in[12];
    const float* bn_m    = (const float*)d_in[13];
    const float* bn_v    = (const float*)d_in[14];

    char* ws = (char*)d_ws;
    unsigned short* VO     = (unsigned short*)(ws);
    unsigned short* y      = (unsigned short*)(ws + 25165824);
    unsigned short* Wallbf = (unsigned short*)(ws + 41943040);
    unsigned short* Woutbf = (unsigned short*)(ws + 42139648);
    float*          ball   = (float*)(ws + 42270720);
    float*          bout   = (float*)(ws + 42272256);
    float* out = (float*)d_out;

    prep_all_kernel<<<43, 256, 0, stream>>>(cv1_w, cv1_b, value_w, value_b, dw_w, dw_b,
                                            om_w, om_b, out_w, cv2_w,
                                            bn_g, bn_b, bn_m, bn_v,
                                            Wallbf, ball, Woutbf, bout);
    gemm_vo_kernel<<<dim3(3, 256), 256, 0, stream>>>(x, Wallbf, ball, VO);
    dcn_kernel<<<4096, 256, 0, stream>>>(VO, y);
    gemm_out_kernel<<<dim3(2, 256), 256, 0, stream>>>(Woutbf, y, bout, out);
}

// Round 13
// 89.013 us; speedup vs baseline: 1.4783x; 1.0752x over previous
//
#include <hip/hip_runtime.h>
#include <hip/hip_bf16.h>
#include <math.h>

#define NN    8
#define HH    64
#define WW    64
#define HW    4096
#define NHW   32768
#define DALL  384     // 256 value + 112 om + 16 pad
#define EPSBN 1e-5f

typedef __attribute__((ext_vector_type(8))) short short8v;
typedef __attribute__((ext_vector_type(4))) float f32x4;
typedef __attribute__((ext_vector_type(2))) float f32x2;

__device__ __forceinline__ float b2f(unsigned short u) {
    union { unsigned int i; float f; } v; v.i = ((unsigned int)u) << 16; return v.f;
}
__device__ __forceinline__ unsigned short f2b(float f) {
    __hip_bfloat16 h = __float2bfloat16(f);
    return *reinterpret_cast<const unsigned short*>(&h);
}
// dword of 2 bf16 -> f32x2 (lo, hi)
__device__ __forceinline__ f32x2 bf2x(int u) {
    union { int i; float f; } a, b;
    a.i = u << 16;
    b.i = u & 0xffff0000;
    f32x2 r; r[0] = a.f; r[1] = b.f; return r;
}

// Workspace layout (bytes):
//  VO     [NHW][384] bf16  @ 0          (25165824)
//  Wallbf [384][256] bf16  @ 25165824   (196608)
//  Woutbf [256][256] bf16  @ 25362432   (131072)
//  ball   [384] f32        @ 25493504   (1536)
//  bout   [256] f32        @ 25495040   (1024)

// ---------------- prep: fold weights (f32 math, 4-way ILP) — round-6 version ----------------
__global__ __launch_bounds__(256)
void prep_kernel(const float* __restrict__ cv1_w, const float* __restrict__ cv1_b,
                 const float* __restrict__ value_w, const float* __restrict__ value_b,
                 const float* __restrict__ dw_w, const float* __restrict__ dw_b,
                 const float* __restrict__ om_w, const float* __restrict__ om_b,
                 const float* __restrict__ out_w, const float* __restrict__ cv2_w,
                 const float* __restrict__ bn_g, const float* __restrict__ bn_b,
                 const float* __restrict__ bn_m, const float* __restrict__ bn_v,
                 unsigned short* __restrict__ Wallbf, float* __restrict__ ball,
                 unsigned short* __restrict__ Woutbf, float* __restrict__ bout)
{
    int job = blockIdx.x * 256 + threadIdx.x;
    if (job < 65536) {                          // Wv = value_w @ cv1_w
        int d = job >> 8, cc = job & 255;
        float s0=0.f, s1=0.f, s2=0.f, s3=0.f;
        for (int e = 0; e < 256; e += 4) {
            float4 wv = *reinterpret_cast<const float4*>(&value_w[d*256+e]);
            s0 = fmaf(wv.x, cv1_w[(e+0)*256+cc], s0);
            s1 = fmaf(wv.y, cv1_w[(e+1)*256+cc], s1);
            s2 = fmaf(wv.z, cv1_w[(e+2)*256+cc], s2);
            s3 = fmaf(wv.w, cv1_w[(e+3)*256+cc], s3);
        }
        Wallbf[job] = f2b((s0+s1)+(s2+s3));
    } else if (job < 94208) {                   // Wom = om_w.diag(dw_w) @ cv1_w
        int idx = job - 65536;
        int o = idx >> 8, cc = idx & 255;
        float s0=0.f, s1=0.f, s2=0.f, s3=0.f;
        for (int e = 0; e < 256; e += 4) {
            float4 wv = *reinterpret_cast<const float4*>(&om_w[o*256+e]);
            float4 dv = *reinterpret_cast<const float4*>(&dw_w[e]);
            s0 = fmaf(wv.x*dv.x, cv1_w[(e+0)*256+cc], s0);
            s1 = fmaf(wv.y*dv.y, cv1_w[(e+1)*256+cc], s1);
            s2 = fmaf(wv.z*dv.z, cv1_w[(e+2)*256+cc], s2);
            s3 = fmaf(wv.w*dv.w, cv1_w[(e+3)*256+cc], s3);
        }
        Wallbf[job] = f2b((s0+s1)+(s2+s3));
    } else if (job < 98304) {                   // pad rows 368..383
        Wallbf[job] = 0;
    } else if (job < 163840) {                  // Wout = diag(s) cv2_w @ out_w
        int idx = job - 98304;
        int d = idx >> 8, cc = idx & 255;
        float s0=0.f, s1=0.f, s2=0.f, s3=0.f;
        for (int e = 0; e < 256; e += 4) {
            float4 wv = *reinterpret_cast<const float4*>(&cv2_w[d*256+e]);
            s0 = fmaf(wv.x, out_w[(e+0)*256+cc], s0);
            s1 = fmaf(wv.y, out_w[(e+1)*256+cc], s1);
            s2 = fmaf(wv.z, out_w[(e+2)*256+cc], s2);
            s3 = fmaf(wv.w, out_w[(e+3)*256+cc], s3);
        }
        float sc = bn_g[d] * rsqrtf(bn_v[d] + EPSBN);
        Woutbf[idx] = f2b(((s0+s1)+(s2+s3)) * sc);
    } else if (job < 164096) {                  // bv
        int d = job - 163840;
        float s = value_b[d];
        for (int e = 0; e < 256; ++e) s = fmaf(value_w[d*256+e], cv1_b[e], s);
        ball[d] = s;
    } else if (job < 164208) {                  // bom
        int o = job - 164096;
        float s = om_b[o];
        for (int e = 0; e < 256; ++e)
            s = fmaf(om_w[o*256+e], fmaf(dw_w[e], cv1_b[e], dw_b[e]), s);
        ball[256 + o] = s;
    } else if (job < 164224) {                  // ball pad
        ball[368 + job - 164208] = 0.f;
    } else if (job < 164480) {                  // bout
        int d = job - 164224;
        float sc = bn_g[d] * rsqrtf(bn_v[d] + EPSBN);
        bout[d] = fmaf(-bn_m[d], sc, bn_b[d]);
    }
}

// ---------------- GEMM1 (fused x-transpose): VO = bf16(x)^T @ Wallbf^T + ball ----------------
__global__ __launch_bounds__(256)
void gemm_vo_kernel(const float* __restrict__ x, const unsigned short* __restrict__ Wallbf,
                    const float* __restrict__ ball, unsigned short* __restrict__ VO)
{
    __shared__ unsigned short As[8192];
    __shared__ unsigned short Bs[8192];
    int t = threadIdx.x;
    int m0 = blockIdx.y * 128;   // pixel tile
    int n0 = blockIdx.x * 128;   // output-channel tile
    int nimg = m0 >> 12, hw0 = m0 & 4095;
    int lane = t & 63;
    int wv = t >> 6;
    int wr = wv >> 1, wc = wv & 1;
    int r_l = lane & 15, kg_l = lane >> 4;
    int ci = t >> 6;             // c-chunk (16 ch) for A staging
    int l  = t & 63;             // row-pair for A staging

    const float* xbase = x + (size_t)(nimg * 256) * 4096 + hw0;

    f32x4 acc[4][4] = {};

    for (int kt = 0; kt < 4; ++kt) {
        int c0 = kt * 64;
        float2 val[16];
        #pragma unroll
        for (int i = 0; i < 16; ++i)
            val[i] = *reinterpret_cast<const float2*>(
                &xbase[(size_t)(c0 + ci*16 + i) * 4096 + 2*l]);
        __syncthreads();   // prior MFMA reads done before overwrite
        #pragma unroll
        for (int rsel = 0; rsel < 2; ++rsel) {
            int row = 2*l + rsel;
            #pragma unroll
            for (int kgi = 0; kgi < 2; ++kgi) {
                int kg = ci*2 + kgi;
                short8v s;
                #pragma unroll
                for (int j = 0; j < 8; ++j)
                    s[j] = (short)f2b(rsel ? val[kgi*8+j].y : val[kgi*8+j].x);
                *reinterpret_cast<short8v*>(&As[row*64 + ((kg ^ (row & 7)) << 3)]) = s;
            }
        }
        #pragma unroll
        for (int i = 0; i < 4; ++i) {
            int idx = t + i*256;
            int row = idx >> 3, kg = idx & 7;
            *reinterpret_cast<short8v*>(&Bs[row*64 + ((kg ^ (row & 7)) << 3)]) =
                *reinterpret_cast<const short8v*>(&Wallbf[(size_t)(n0 + row)*256 + c0 + kg*8]);
        }
        __syncthreads();
        #pragma unroll
        for (int ks = 0; ks < 2; ++ks) {
            short8v af[4], bfr[4];
            #pragma unroll
            for (int m = 0; m < 4; ++m) {
                int row = wr*64 + m*16 + r_l;
                af[m] = *reinterpret_cast<const short8v*>(
                    &As[row*64 + (((ks*4 + kg_l) ^ (row & 7)) << 3)]);
            }
            #pragma unroll
            for (int n = 0; n < 4; ++n) {
                int row = wc*64 + n*16 + r_l;
                bfr[n] = *reinterpret_cast<const short8v*>(
                    &Bs[row*64 + (((ks*4 + kg_l) ^ (row & 7)) << 3)]);
            }
            #pragma unroll
            for (int m = 0; m < 4; ++m)
                #pragma unroll
                for (int n = 0; n < 4; ++n)
                    acc[m][n] = __builtin_amdgcn_mfma_f32_16x16x32_bf16(af[m], bfr[n], acc[m][n], 0, 0, 0);
        }
    }

    #pragma unroll
    for (int n = 0; n < 4; ++n) {
        int d = n0 + wc*64 + n*16 + r_l;
        float bb = ball[d];
        #pragma unroll
        for (int m = 0; m < 4; ++m) {
            int pr = m0 + wr*64 + m*16 + (kg_l << 2);
            #pragma unroll
            for (int r = 0; r < 4; ++r)
                VO[(size_t)(pr + r)*384 + d] = f2b(acc[m][n][r] + bb);
        }
    }
}

// ---------------- fused DCNv4 + GEMM2: out = SiLU(Wout @ dcn(VO)^T + bout) ----------------
// Block = 64 px (one image row) x 512 threads.
// Phase 1: dcn (round-6 inner loop, direct global gathers) -> y tile in LDS,
//          written directly in the GEMM-B swizzled layout (4 sections [g][64px][64k]).
// Phase 2: 8-wave MFMA, A = Woutbf staged per K-tile into a region union-shared
//          with phase-1's om buffer; B read straight from the LDS y tile.
// 64 KB LDS, __launch_bounds__(512,4) -> 2 blocks/CU; phase overlap across blocks.
__global__ __launch_bounds__(512, 4)
void dcn_gemm_kernel(const unsigned short* __restrict__ VO,
                     const unsigned short* __restrict__ Woutbf,
                     const float* __restrict__ bout, float* __restrict__ out)
{
    __shared__ unsigned short y_lds[16384];   // 32 KB: 4 sections x [64px][64k], swizzled
    __shared__ char u_buf[32768];             // 32 KB: phase1 om_s f32[64][108] | phase2 As
    float* om_s = reinterpret_cast<float*>(u_buf);
    unsigned short* As = reinterpret_cast<unsigned short*>(u_buf);

    int t = threadIdx.x;
    int bid = blockIdx.x;                     // 512 blocks = 8 XCD x 64
    int logical = ((bid & 7) << 6) + (bid >> 3);   // image == XCD
    int p0 = logical * 64;
    int nimg = p0 >> 12;
    int hw0 = p0 & 4095;
    int h = hw0 >> 6;                         // single image row; w == px

    const unsigned short* vimg = VO + (size_t)nimg * (HW * (size_t)DALL);

    // ---- stage om for 64 px into om_s (f32) ----
    for (int i = t; i < 6912; i += 512) {
        int pl = i / 108, j = i - pl * 108;
        om_s[pl * 108 + j] = b2f(vimg[(size_t)(hw0 + pl) * DALL + 256 + j]);
    }
    __syncthreads();

    // ---- phase 1: dcn, 4 slots per thread ----
    int ch8 = t & 7;
    #pragma unroll
    for (int iter = 0; iter < 4; ++iter) {
        int slotIdx = iter * 64 + (t >> 3);   // 0..255
        int px = slotIdx >> 2, g = slotIdx & 3;
        int w = px;
        const unsigned short* vbase = vimg + g*64 + ch8*8;
        const float* o = om_s + px*108 + g*27;

        f32x2 acc2[4] = {};
        #pragma unroll
        for (int k = 0; k < 9; ++k) {
            float dxo = o[2*k], dyo = o[2*k+1], m = o[18+k];
            float pxf = (float)(w + (k % 3) - 1) + dxo;
            float pyf = (float)(h + (k / 3) - 1) + dyo;
            float x0f = floorf(pxf), y0f = floorf(pyf);
            float fx = pxf - x0f, fy = pyf - y0f;
            int x0 = (int)x0f, y0 = (int)y0f;
            #pragma unroll
            for (int dyy = 0; dyy < 2; ++dyy) {
                #pragma unroll
                for (int dxx = 0; dxx < 2; ++dxx) {
                    int yy = y0 + dyy, xx = x0 + dxx;
                    bool valid = (yy >= 0) & (yy < HH) & (xx >= 0) & (xx < WW);
                    float wgt = (dyy ? fy : 1.f - fy) * (dxx ? fx : 1.f - fx);
                    float wmc = valid ? (m * wgt) : 0.f;
                    int yc = min(max(yy, 0), HH - 1);
                    int xc = min(max(xx, 0), WW - 1);
                    int4 v = *reinterpret_cast<const int4*>(
                        &vbase[((yc << 6) + xc) * DALL]);
                    f32x2 wm2; wm2[0] = wmc; wm2[1] = wmc;
                    int vv[4] = {v.x, v.y, v.z, v.w};
                    #pragma unroll
                    for (int q = 0; q < 4; ++q)
                        acc2[q] += bf2x(vv[q]) * wm2;
                }
            }
        }
        short8v ov;
        #pragma unroll
        for (int q = 0; q < 4; ++q) {
            ov[2*q]   = (short)f2b(acc2[q][0]);
            ov[2*q+1] = (short)f2b(acc2[q][1]);
        }
        // write into section g, row px, kg = ch8 (B-swizzled)
        *reinterpret_cast<short8v*>(
            &y_lds[g*4096 + px*64 + ((ch8 ^ (px & 7)) << 3)]) = ov;
    }

    // ---- phase 2: GEMM (M=256 d, N=64 px, K=256) ----
    int lane = t & 63;
    int wv = t >> 6;                          // 8 waves
    int wr = wv >> 1, wc = wv & 1;            // wr: 64-d band, wc: 32-px band
    int r_l = lane & 15, kg_l = lane >> 4;

    f32x4 acc[4][2] = {};
    for (int kt = 0; kt < 4; ++kt) {
        int c0 = kt * 64;
        __syncthreads();   // om_s/As free (phase1 done or prior kt MFMA done)
        #pragma unroll
        for (int i = 0; i < 4; ++i) {
            int idx = t + i * 512;            // 2048 jobs: row 0..255, kg 0..7
            int row = idx >> 3, kg = idx & 7;
            *reinterpret_cast<short8v*>(&As[row*64 + ((kg ^ (row & 7)) << 3)]) =
                *reinterpret_cast<const short8v*>(&Woutbf[(size_t)row*256 + c0 + kg*8]);
        }
        __syncthreads();
        #pragma unroll
        for (int ks = 0; ks < 2; ++ks) {
            short8v af[4], bfr[2];
            #pragma unroll
            for (int m = 0; m < 4; ++m) {
                int row = wr*64 + m*16 + r_l;
                af[m] = *reinterpret_cast<const short8v*>(
                    &As[row*64 + (((ks*4 + kg_l) ^ (row & 7)) << 3)]);
            }
            #pragma unroll
            for (int n = 0; n < 2; ++n) {
                int row = wc*32 + n*16 + r_l;
                bfr[n] = *reinterpret_cast<const short8v*>(
                    &y_lds[kt*4096 + row*64 + (((ks*4 + kg_l) ^ (row & 7)) << 3)]);
            }
            #pragma unroll
            for (int m = 0; m < 4; ++m)
                #pragma unroll
                for (int n = 0; n < 2; ++n)
                    acc[m][n] = __builtin_amdgcn_mfma_f32_16x16x32_bf16(af[m], bfr[n], acc[m][n], 0, 0, 0);
        }
    }

    // ---- epilogue: bias + SiLU + NCHW f32 store ----
    #pragma unroll
    for (int m = 0; m < 4; ++m) {
        int dbase = wr*64 + m*16 + (kg_l << 2);
        #pragma unroll
        for (int r = 0; r < 4; ++r) {
            int d = dbase + r;
            float bb = bout[d];
            #pragma unroll
            for (int n = 0; n < 2; ++n) {
                int pcol = wc*32 + n*16 + r_l;
                float z = acc[m][n][r] + bb;
                float sv = z / (1.f + __expf(-z));
                out[((size_t)(nimg*256 + d))*4096 + hw0 + pcol] = sv;
            }
        }
    }
}

extern "C" void kernel_launch(void* const* d_in, const int* in_sizes, int n_in,
                              void* d_out, int out_size, void* d_ws, size_t ws_size,
                              hipStream_t stream) {
    const float* x       = (const float*)d_in[0];
    const float* cv1_w   = (const float*)d_in[1];
    const float* cv1_b   = (const float*)d_in[2];
    const float* value_w = (const float*)d_in[3];
    const float* value_b = (const float*)d_in[4];
    const float* dw_w    = (const float*)d_in[5];
    const float* dw_b    = (const float*)d_in[6];
    const float* om_w    = (const float*)d_in[7];
    const float* om_b    = (const float*)d_in[8];
    const float* out_w   = (const float*)d_in[9];
    const float* cv2_w   = (const float*)d_in[10];
    const float* bn_g    = (const float*)d_in[11];
    const float* bn_b    = (const float*)d_in[12];
    const float* bn_m    = (const float*)d_in[13];
    const float* bn_v    = (const float*)d_in[14];

    char* ws = (char*)d_ws;
    unsigned short* VO     = (unsigned short*)(ws);
    unsigned short* Wallbf = (unsigned short*)(ws + 25165824);
    unsigned short* Woutbf = (unsigned short*)(ws + 25362432);
    float*          ball   = (float*)(ws + 25493504);
    float*          bout   = (float*)(ws + 25495040);
    float* out = (float*)d_out;

    prep_kernel<<<643, 256, 0, stream>>>(cv1_w, cv1_b, value_w, value_b, dw_w, dw_b,
                                         om_w, om_b, out_w, cv2_w,
                                         bn_g, bn_b, bn_m, bn_v,
                                         Wallbf, ball, Woutbf, bout);
    gemm_vo_kernel<<<dim3(3, 256), 256, 0, stream>>>(x, Wallbf, ball, VO);
    dcn_gemm_kernel<<<512, 512, 0, stream>>>(VO, Woutbf, bout, out);
}